// Round 7
// baseline (449.540 us; speedup 1.0000x reference)
//
#include <hip/hip_runtime.h>
#include <hip/hip_bf16.h>
#include <math.h>

#define NB 32
#define NL 1024
#define ND 128
#define NF 16
#define DT_RANK 8
#define NS 2
#define DCONV 4
#define NCHUNK 32
#define CLEN 32   // NL / NCHUNK

typedef __attribute__((ext_vector_type(8))) short bf16x8;
typedef __attribute__((ext_vector_type(4))) float f32x4;

__device__ inline unsigned short f2bf(float x) {
    unsigned u = __float_as_uint(x);
    return (unsigned short)((u + 0x7fffu + ((u >> 16) & 1u)) >> 16);   // RNE
}
__device__ inline unsigned pk2(float a, float b) {
    return (unsigned)f2bf(a) | ((unsigned)f2bf(b) << 16);
}

// ---------------------------------------------------------------------------
// FiLM conditioning (blocks 0..NB-1) + weight fp32->bf16 conversion
// (blocks NB..NB+95): Wi = in_proj_w bf16 (32768), Wo = out_proj_w bf16 (16384).
// ---------------------------------------------------------------------------
__global__ __launch_bounds__(128)
void film_wconv_kernel(const float* __restrict__ gpt_emb,
                       const float* __restrict__ w1, const float* __restrict__ b1,
                       const float* __restrict__ w2, const float* __restrict__ b2,
                       float* __restrict__ gb,
                       const float* __restrict__ Wi_f, const float* __restrict__ Wo_f,
                       unsigned short* __restrict__ Wi, unsigned short* __restrict__ Wo)
{
    int blk = blockIdx.x, t = threadIdx.x;
    if (blk >= NB) {
        int i = (blk - NB) * 512 + t * 4;
        if (i < 2 * ND * ND) {
            float4 v = *(const float4*)&Wi_f[i];
            int2 pv = { (int)pk2(v.x, v.y), (int)pk2(v.z, v.w) };
            *(int2*)&Wi[i] = pv;
        } else {
            int j = i - 2 * ND * ND;
            float4 v = *(const float4*)&Wo_f[j];
            int2 pv = { (int)pk2(v.x, v.y), (int)pk2(v.z, v.w) };
            *(int2*)&Wo[j] = pv;
        }
        return;
    }
    int b = blk;
    __shared__ float sg[ND];
    __shared__ float sh[ND];
    sg[t] = gpt_emb[b * ND + t];
    __syncthreads();
    float a = b1[t];
    #pragma unroll 8
    for (int d = 0; d < ND; ++d) a += sg[d] * w1[t * ND + d];
    sh[t] = a / (1.f + expf(-a));   // silu
    __syncthreads();
    float g0 = b2[t], g1 = b2[ND + t];
    #pragma unroll 8
    for (int j = 0; j < ND; ++j) {
        float hv = sh[j];
        g0 += hv * w2[t * ND + j];
        g1 += hv * w2[(ND + t) * ND + j];
    }
    gb[b * 256 + t]      = g0;
    gb[b * 256 + ND + t] = g1;
}

// ---------------------------------------------------------------------------
// Fused RMSNorm -> cross-attn -> FiLM -> in_proj MFMA GEMM.
// Block = 64 rows of one batch, 256 threads (4 waves).
// h built in LDS bf16; in_proj W read as bf16 fragments from global (L2).
// Outputs: x1 (fp32, for final residual), xr (fp32 [l][256] = xin|res).
// ---------------------------------------------------------------------------
__global__ __launch_bounds__(256)
void pre_gemm_kernel(const float* __restrict__ x, const float* __restrict__ fg_emb,
                     const float* __restrict__ norm_w, const float* __restrict__ gb,
                     const unsigned short* __restrict__ Wi,
                     float* __restrict__ x1_out, float* __restrict__ xr_out)
{
    __shared__ float fgs[NF * ND];                       // 8 KB
    __shared__ float nws[ND];
    __shared__ float gbs[2 * ND];
    __shared__ __align__(16) unsigned short h_lds[64 * 136];   // 17.4 KB
    int b = blockIdx.y, l0 = blockIdx.x * 64;
    int t = threadIdx.x;
    {   // stage fg_emb, norm_w, gb
        const float* src = fg_emb + (long)b * NF * ND;
        *(float4*)&fgs[t * 8]     = *(const float4*)&src[t * 8];
        *(float4*)&fgs[t * 8 + 4] = *(const float4*)&src[t * 8 + 4];
        if (t < ND) nws[t] = norm_w[t];
        gbs[t] = gb[b * 256 + t];
    }
    int r = t >> 2, c = t & 3;
    const float* xp = x + ((long)b * NL + l0 + r) * ND + c * 32;
    float xv[32];
    float ss = 0.f;
    #pragma unroll
    for (int q = 0; q < 8; ++q) {
        float4 v = *(const float4*)(xp + q * 4);
        xv[q * 4] = v.x; xv[q * 4 + 1] = v.y; xv[q * 4 + 2] = v.z; xv[q * 4 + 3] = v.w;
        ss += v.x * v.x + v.y * v.y + v.z * v.z + v.w * v.w;
    }
    ss += __shfl_xor(ss, 1);
    ss += __shfl_xor(ss, 2);
    __syncthreads();
    float rinv = rsqrtf(ss * (1.f / (float)ND) + 1e-5f);
    #pragma unroll
    for (int e = 0; e < 32; ++e) xv[e] = xv[e] * rinv * nws[c * 32 + e];
    float* x1p = x1_out + ((long)b * NL + l0 + r) * ND + c * 32;
    #pragma unroll
    for (int q = 0; q < 8; ++q) {
        float4 v = { xv[q * 4], xv[q * 4 + 1], xv[q * 4 + 2], xv[q * 4 + 3] };
        *(float4*)(x1p + q * 4) = v;
    }
    // attention scores (4 lanes per row, butterfly-reduced)
    float sc[NF];
    #pragma unroll
    for (int f = 0; f < NF; ++f) {
        const float* fp = &fgs[f * ND + c * 32];
        float p = 0.f;
        #pragma unroll
        for (int e = 0; e < 32; ++e) p += xv[e] * fp[e];
        p += __shfl_xor(p, 1);
        p += __shfl_xor(p, 2);
        sc[f] = p * 0.08838834764831845f;   // 1/sqrt(128)
    }
    float mx = sc[0];
    #pragma unroll
    for (int f = 1; f < NF; ++f) mx = fmaxf(mx, sc[f]);
    float wsum = 0.f;
    #pragma unroll
    for (int f = 0; f < NF; ++f) { sc[f] = expf(sc[f] - mx); wsum += sc[f]; }
    float inv = 1.f / wsum;
    #pragma unroll
    for (int f = 0; f < NF; ++f) sc[f] *= inv;
    // h = x1 + attn@fg, FiLM, -> bf16 LDS
    unsigned* hrow = (unsigned*)h_lds;
    int hbase = (r * 136 + c * 32) >> 1;
    #pragma unroll
    for (int e = 0; e < 32; e += 2) {
        int d0 = c * 32 + e;
        float h0 = xv[e], h1 = xv[e + 1];
        #pragma unroll
        for (int f = 0; f < NF; ++f) {
            const float* fp = &fgs[f * ND + d0];
            h0 += sc[f] * fp[0];
            h1 += sc[f] * fp[1];
        }
        h0 = h0 * gbs[d0]     + gbs[128 + d0];
        h1 = h1 * gbs[d0 + 1] + gbs[128 + d0 + 1];
        hrow[hbase + (e >> 1)] = pk2(h0, h1);
    }
    __syncthreads();
    // MFMA: 4 waves x 16 rows x 256 cols
    int lane = t & 63, w = t >> 6, lrow = lane & 15, lgrp = lane >> 4;
    const unsigned short* Ab = h_lds + (w * 16 + lrow) * 136 + lgrp * 8;
    bf16x8 a[4];
    #pragma unroll
    for (int c4 = 0; c4 < 4; ++c4) a[c4] = *(const bf16x8*)(Ab + c4 * 32);
    f32x4 acc[16];
    #pragma unroll
    for (int i = 0; i < 16; ++i) acc[i] = (f32x4){0.f, 0.f, 0.f, 0.f};
    #pragma unroll
    for (int nb = 0; nb < 16; ++nb) {
        #pragma unroll
        for (int c4 = 0; c4 < 4; ++c4) {
            bf16x8 bb = *(const bf16x8*)(Wi + (nb * 16 + lrow) * ND + lgrp * 8 + c4 * 32);
            acc[nb] = __builtin_amdgcn_mfma_f32_16x16x32_bf16(a[c4], bb, acc[nb], 0, 0, 0);
        }
    }
    float* Cp = xr_out + ((long)b * NL + l0 + w * 16 + lgrp * 4) * 256 + lrow;
    #pragma unroll
    for (int nb = 0; nb < 16; ++nb)
        #pragma unroll
        for (int reg = 0; reg < 4; ++reg)
            Cp[(long)reg * 256 + nb * 16] = acc[nb][reg];
}

// ---------------------------------------------------------------------------
// Fused causal conv1d + SiLU + x_proj + dt_proj + softplus + delta-transpose.
// Block = 64 rows of one batch, 256 threads.
// Outputs: xs fp32 [b][l][d], dbt bf16 [b][d][l], bc [b][l][4].
// ---------------------------------------------------------------------------
__global__ __launch_bounds__(256)
void conv_xproj_kernel(const float* __restrict__ xr,
                       const float* __restrict__ conv_w, const float* __restrict__ conv_b,
                       const float* __restrict__ x_proj_w,
                       const float* __restrict__ dt_proj_w, const float* __restrict__ dt_proj_b,
                       float* __restrict__ xs_out, unsigned short* __restrict__ dbt,
                       float* __restrict__ bc_out)
{
    __shared__ float xin[67 * 132];            // 35.4 KB; reused as T after conv
    __shared__ float xsl[64 * 129];            // 33 KB
    unsigned short* T = (unsigned short*)xin;  // [128][72] shorts
    int b = blockIdx.y, l0 = blockIdx.x * 64;
    int t = threadIdx.x;
    for (int i = t; i < 67 * 32; i += 256) {
        int rr = i >> 5, c4 = i & 31;
        int l = l0 - 3 + rr;
        float4 v = {0.f, 0.f, 0.f, 0.f};
        if (l >= 0) v = *(const float4*)(xr + ((long)b * NL + l) * 256 + c4 * 4);
        *(float4*)&xin[rr * 132 + c4 * 4] = v;
    }
    __syncthreads();
    {   // conv + silu (d-contiguous mapping: 2-way bank = free)
        int d = t & 127, rg = t >> 7;
        float w0 = conv_w[d * 4], w1 = conv_w[d * 4 + 1];
        float w2 = conv_w[d * 4 + 2], w3 = conv_w[d * 4 + 3];
        float cb = conv_b[d];
        for (int r = rg; r < 64; r += 2) {
            float acc = cb + w0 * xin[r * 132 + d] + w1 * xin[(r + 1) * 132 + d]
                           + w2 * xin[(r + 2) * 132 + d] + w3 * xin[(r + 3) * 132 + d];
            float xsv = acc / (1.f + expf(-acc));
            xsl[r * 129 + d] = xsv;
            xs_out[((long)b * NL + l0 + r) * ND + d] = xsv;
        }
    }
    __syncthreads();
    {   // x_proj (12 dots) + dt_proj + softplus; delta -> T (transpose)
        int r = t >> 2, c = t & 3;
        float dbl[12];
        #pragma unroll
        for (int j = 0; j < 12; ++j) {
            const float* wr = x_proj_w + j * ND + c * 32;
            const float* xp = &xsl[r * 129 + c * 32];
            float p = 0.f;
            #pragma unroll
            for (int e = 0; e < 32; ++e) p += xp[e] * wr[e];
            p += __shfl_xor(p, 1);
            p += __shfl_xor(p, 2);
            dbl[j] = p;
        }
        if (c == 0) {
            float4 v = { dbl[8], dbl[9], dbl[10], dbl[11] };
            *(float4*)(bc_out + ((long)b * NL + l0 + r) * 4) = v;
        }
        #pragma unroll
        for (int e = 0; e < 32; ++e) {
            int d = c * 32 + e;
            float a = dt_proj_b[d];
            #pragma unroll
            for (int q = 0; q < DT_RANK; ++q) a += dbl[q] * dt_proj_w[d * DT_RANK + q];
            float dl = (a > 20.f) ? a : log1pf(expf(a));   // softplus
            T[d * 72 + r] = f2bf(dl);
        }
    }
    __syncthreads();
    {   // coalesced dbt store
        int dr = t >> 1, half = t & 1;
        unsigned short* dst = dbt + ((long)b * ND + dr) * NL + l0 + half * 32;
        const unsigned short* src = &T[dr * 72 + half * 32];
        #pragma unroll
        for (int q = 0; q < 4; ++q)
            *(int4*)(dst + q * 8) = *(const int4*)(src + q * 8);
    }
}

// ---------------------------------------------------------------------------
// delta_p GEMM (MFMA bf16): dp[b] = dis[b][1024x1024] @ delta[b][1024x128].
// ---------------------------------------------------------------------------
__global__ __launch_bounds__(256)
void dpgemm_kernel(const float* __restrict__ dis, const unsigned short* __restrict__ dbt,
                   float* __restrict__ dp)
{
    __shared__ __align__(16) unsigned short As[64 * 72];
    __shared__ __align__(16) unsigned short Bs[128 * 72];
    int b = blockIdx.y, m0 = blockIdx.x * 64;
    int t = threadIdx.x;
    int lane = t & 63, w = t >> 6, lrow = lane & 15, lgrp = lane >> 4;
    int ar = t >> 2, ac = t & 3;
    int br = t >> 1, bh = t & 1;
    const float* Ag = dis + ((long)b * NL + m0 + ar) * NL;
    const unsigned short* Bg = dbt + ((long)b * ND + br) * NL;
    f32x4 acc[8];
    #pragma unroll
    for (int i = 0; i < 8; ++i) acc[i] = (f32x4){0.f, 0.f, 0.f, 0.f};
    const char* Ar = (const char*)As + (w * 16 + lrow) * 144 + lgrp * 16;
    const char* Br = (const char*)Bs + lrow * 144 + lgrp * 16;

    for (int k0 = 0; k0 < NL; k0 += 64) {
        #pragma unroll
        for (int q = 0; q < 4; ++q) {
            float4 v = *(const float4*)(Ag + k0 + ac * 4 + q * 16);
            unsigned long long pv = (unsigned long long)pk2(v.x, v.y)
                                  | ((unsigned long long)pk2(v.z, v.w) << 32);
            *(unsigned long long*)((char*)As + ar * 144 + ac * 8 + q * 32) = pv;
        }
        #pragma unroll
        for (int j = 0; j < 4; ++j) {
            int slot = bh * 4 + j;
            *(int4*)((char*)Bs + br * 144 + slot * 16) =
                *(const int4*)(Bg + k0 + slot * 8);
        }
        __syncthreads();
        bf16x8 a0 = *(const bf16x8*)(Ar);
        bf16x8 a1 = *(const bf16x8*)(Ar + 64);
        #pragma unroll
        for (int nb = 0; nb < 8; ++nb) {
            bf16x8 b0 = *(const bf16x8*)(Br + nb * 16 * 144);
            bf16x8 b1 = *(const bf16x8*)(Br + nb * 16 * 144 + 64);
            acc[nb] = __builtin_amdgcn_mfma_f32_16x16x32_bf16(a0, b0, acc[nb], 0, 0, 0);
            acc[nb] = __builtin_amdgcn_mfma_f32_16x16x32_bf16(a1, b1, acc[nb], 0, 0, 0);
        }
        __syncthreads();
    }
    float* Cp = dp + ((long)b * NL + m0 + w * 16 + lgrp * 4) * ND + lrow;
    #pragma unroll
    for (int nb = 0; nb < 8; ++nb)
        #pragma unroll
        for (int r = 0; r < 4; ++r)
            Cp[(long)r * ND + nb * 16] = acc[nb][r];
}

// ---------------------------------------------------------------------------
// Chunked parallel scan, 3 phases.  pass3 writes yg as bf16 (A of out-GEMM).
// ---------------------------------------------------------------------------
__global__ __launch_bounds__(128)
void scan_pass1(const float* __restrict__ delta_p, const float* __restrict__ xs,
                const float* __restrict__ bc, const float* __restrict__ A_log,
                float* __restrict__ Pc, float* __restrict__ Sc)
{
    int c = blockIdx.x, b = blockIdx.y, d = threadIdx.x;
    float A0 = -expf(A_log[d * NS + 0]);
    float A1 = -expf(A_log[d * NS + 1]);
    int l0 = c * CLEN;
    const float* dp_p = delta_p + ((long)b * NL + l0) * ND + d;
    const float* xs_p = xs      + ((long)b * NL + l0) * ND + d;
    const float* bc_p = bc      + ((long)b * NL + l0) * 4;
    float p0 = 1.f, p1 = 1.f, s0 = 0.f, s1 = 0.f;
    #pragma unroll 4
    for (int t = 0; t < CLEN; ++t) {
        float dp = dp_p[(long)t * ND];
        float xv = xs_p[(long)t * ND];
        float B0 = bc_p[t * 4 + 0], B1 = bc_p[t * 4 + 1];
        float a0 = expf(dp * A0), a1 = expf(dp * A1);
        float u = dp * xv;
        s0 = a0 * s0 + u * B0;
        s1 = a1 * s1 + u * B1;
        p0 *= a0;
        p1 *= a1;
    }
    long o = ((long)(b * NCHUNK + c) * 2) * ND + d;
    Pc[o] = p0; Pc[o + ND] = p1;
    Sc[o] = s0; Sc[o + ND] = s1;
}

__global__ __launch_bounds__(128)
void scan_combine(const float* __restrict__ Pc, const float* __restrict__ Sc,
                  float* __restrict__ init)
{
    int b = blockIdx.x, d = threadIdx.x;
    float s0 = 0.f, s1 = 0.f;
    #pragma unroll 4
    for (int c = 0; c < NCHUNK; ++c) {
        long o = ((long)(b * NCHUNK + c) * 2) * ND + d;
        init[o] = s0; init[o + ND] = s1;
        s0 = Pc[o] * s0 + Sc[o];
        s1 = Pc[o + ND] * s1 + Sc[o + ND];
    }
}

__global__ __launch_bounds__(128)
void scan_pass3(const float* __restrict__ delta_p, const float* __restrict__ xs,
                const float* __restrict__ bc, const float* __restrict__ xr,
                const float* __restrict__ A_log, const float* __restrict__ D_skip,
                const float* __restrict__ init, unsigned short* __restrict__ yg)
{
    int c = blockIdx.x, b = blockIdx.y, d = threadIdx.x;
    float A0 = -expf(A_log[d * NS + 0]);
    float A1 = -expf(A_log[d * NS + 1]);
    float Dd = D_skip[d];
    long o = ((long)(b * NCHUNK + c) * 2) * ND + d;
    float s0 = init[o], s1 = init[o + ND];
    int l0 = c * CLEN;
    const float* dp_p  = delta_p + ((long)b * NL + l0) * ND + d;
    const float* xs_p  = xs      + ((long)b * NL + l0) * ND + d;
    const float* bc_p  = bc      + ((long)b * NL + l0) * 4;
    const float* res_p = xr      + ((long)b * NL + l0) * 256 + ND + d;
    unsigned short* yg_p = yg    + ((long)b * NL + l0) * ND + d;
    #pragma unroll 4
    for (int t = 0; t < CLEN; ++t) {
        float dp = dp_p[(long)t * ND];
        float xv = xs_p[(long)t * ND];
        float B0 = bc_p[t * 4 + 0], B1 = bc_p[t * 4 + 1];
        float C0 = bc_p[t * 4 + 2], C1 = bc_p[t * 4 + 3];
        float a0 = expf(dp * A0), a1 = expf(dp * A1);
        float u = dp * xv;
        s0 = a0 * s0 + u * B0;
        s1 = a1 * s1 + u * B1;
        float y = s0 * C0 + s1 * C1 + xv * Dd;
        float r = res_p[(long)t * 256];
        yg_p[(long)t * ND] = f2bf(y * (r / (1.f + expf(-r))));   // y * silu(res)
    }
}

// ---------------------------------------------------------------------------
// out = finite(yg @ out_proj^T) + x1.  A (yg bf16) and B (Wo bf16) both read
// directly from global (L2); no LDS.  Block = 64 rows, 4 waves.
// ---------------------------------------------------------------------------
__global__ __launch_bounds__(256)
void outgemm_kernel(const unsigned short* __restrict__ yg,
                    const unsigned short* __restrict__ Wo,
                    const float* __restrict__ X1, float* __restrict__ out)
{
    int m0 = blockIdx.x * 64;
    int t = threadIdx.x, lane = t & 63, w = t >> 6, lrow = lane & 15, lgrp = lane >> 4;
    const unsigned short* Ap = yg + ((long)(m0 + w * 16 + lrow)) * ND + lgrp * 8;
    bf16x8 a[4];
    #pragma unroll
    for (int c4 = 0; c4 < 4; ++c4) a[c4] = *(const bf16x8*)(Ap + c4 * 32);
    f32x4 acc[8];
    #pragma unroll
    for (int i = 0; i < 8; ++i) acc[i] = (f32x4){0.f, 0.f, 0.f, 0.f};
    #pragma unroll
    for (int nb = 0; nb < 8; ++nb) {
        #pragma unroll
        for (int c4 = 0; c4 < 4; ++c4) {
            bf16x8 bb = *(const bf16x8*)(Wo + (nb * 16 + lrow) * ND + lgrp * 8 + c4 * 32);
            acc[nb] = __builtin_amdgcn_mfma_f32_16x16x32_bf16(a[c4], bb, acc[nb], 0, 0, 0);
        }
    }
    #pragma unroll
    for (int nb = 0; nb < 8; ++nb) {
        #pragma unroll
        for (int reg = 0; reg < 4; ++reg) {
            long m = m0 + w * 16 + lgrp * 4 + reg;
            int n = nb * 16 + lrow;
            float v = acc[nb][reg];
            if (!isfinite(v)) v = 0.f;
            out[m * ND + n] = v + X1[m * ND + n];
        }
    }
}

// ---------------------------------------------------------------------------
extern "C" void kernel_launch(void* const* d_in, const int* in_sizes, int n_in,
                              void* d_out, int out_size, void* d_ws, size_t ws_size,
                              hipStream_t stream)
{
    const float* x         = (const float*)d_in[0];
    const float* dis       = (const float*)d_in[1];
    const float* gpt       = (const float*)d_in[2];
    const float* fg        = (const float*)d_in[3];
    const float* norm_w    = (const float*)d_in[4];
    const float* in_proj_w = (const float*)d_in[5];
    const float* conv_w    = (const float*)d_in[6];
    const float* conv_b    = (const float*)d_in[7];
    const float* x_proj_w  = (const float*)d_in[8];
    const float* dt_proj_w = (const float*)d_in[9];
    const float* dt_proj_b = (const float*)d_in[10];
    const float* A_log     = (const float*)d_in[11];
    const float* D_skip    = (const float*)d_in[12];
    const float* out_proj_w= (const float*)d_in[13];
    const float* film_w1   = (const float*)d_in[14];
    const float* film_b1   = (const float*)d_in[15];
    const float* film_w2   = (const float*)d_in[16];
    const float* film_b2   = (const float*)d_in[17];

    float* ws = (float*)d_ws;
    const size_t S = (size_t)NB * NL * ND;   // 4,194,304
    float* x1      = ws;                     // [S]
    float* xr      = ws + S;                 // [2S]
    float* xs      = ws + 3 * S;             // [S]
    unsigned short* dbt = (unsigned short*)(ws + 4 * S);      // [S] bf16
    float* delta_p = ws + 4 * S + S / 2;     // [S]
    unsigned short* yg = (unsigned short*)(ws + 5 * S + S / 2);  // [S] bf16
    float* bc      = ws + 6 * S;             // [NB*NL*4]
    float* gb      = bc + (size_t)NB * NL * 4;                // [NB*256]
    unsigned short* Wi = (unsigned short*)(gb + (size_t)NB * 256);  // [32768]
    unsigned short* Wo = Wi + 2 * ND * ND;                          // [16384]
    float* Pc      = (float*)(Wo + ND * ND);
    const size_t CS = (size_t)NB * NCHUNK * 2 * ND;           // 262144
    float* Sc      = Pc + CS;
    float* initb   = Pc + 2 * CS;

    film_wconv_kernel<<<NB + 96, 128, 0, stream>>>(
        gpt, film_w1, film_b1, film_w2, film_b2, gb, in_proj_w, out_proj_w, Wi, Wo);

    pre_gemm_kernel<<<dim3(NL / 64, NB), 256, 0, stream>>>(
        x, fg, norm_w, gb, Wi, x1, xr);

    conv_xproj_kernel<<<dim3(NL / 64, NB), 256, 0, stream>>>(
        xr, conv_w, conv_b, x_proj_w, dt_proj_w, dt_proj_b, xs, dbt, bc);

    dpgemm_kernel<<<dim3(16, NB), 256, 0, stream>>>(dis, dbt, delta_p);

    scan_pass1<<<dim3(NCHUNK, NB), 128, 0, stream>>>(delta_p, xs, bc, A_log, Pc, Sc);
    scan_combine<<<NB, 128, 0, stream>>>(Pc, Sc, initb);
    scan_pass3<<<dim3(NCHUNK, NB), 128, 0, stream>>>(
        delta_p, xs, bc, xr, A_log, D_skip, initb, yg);

    outgemm_kernel<<<512, 256, 0, stream>>>(yg, Wo, x1, (float*)d_out);
}